// Round 1
// baseline (268.419 us; speedup 1.0000x reference)
//
#include <hip/hip_runtime.h>
#include <hip/hip_bf16.h>
#include <math.h>

#define B_  4
#define T_  1024
#define C_  768
#define H_  12
#define HD_ 64
#define M_  (B_*T_)     // 4096 rows
#define C3_ (3*C_)      // 2304
#define C4_ (4*C_)      // 3072

typedef __bf16 bf16;
typedef bf16  bf16x8 __attribute__((ext_vector_type(8)));
typedef float f32x4  __attribute__((ext_vector_type(4)));

__device__ __forceinline__ f32x4 mfma16(bf16x8 a, bf16x8 b, f32x4 c) {
    return __builtin_amdgcn_mfma_f32_16x16x32_bf16(a, b, c, 0, 0, 0);
}

#define GLOAD_LDS16(g, l)                                                     \
    __builtin_amdgcn_global_load_lds(                                         \
        (const __attribute__((address_space(1))) void*)(g),                   \
        (__attribute__((address_space(3))) void*)(l), 16, 0, 0)

// ---------------------------------------------------------------------------
// Transpose + cast: in fp32 [K,N] -> out bf16 [N,K]
// ---------------------------------------------------------------------------
__global__ void transpose_cast_kernel(const float* __restrict__ in,
                                      bf16* __restrict__ out, int K, int N) {
    __shared__ float tile[32][33];
    int n0 = blockIdx.x * 32, k0 = blockIdx.y * 32;
    int tx = threadIdx.x, ty = threadIdx.y;  // 32 x 8
#pragma unroll
    for (int i = 0; i < 32; i += 8)
        tile[ty + i][tx] = in[(size_t)(k0 + ty + i) * N + n0 + tx];
    __syncthreads();
#pragma unroll
    for (int i = 0; i < 32; i += 8)
        out[(size_t)(n0 + ty + i) * K + k0 + tx] = (bf16)tile[tx][ty + i];
}

// ---------------------------------------------------------------------------
// LayerNorm: fp32 in [rows, 768] -> bf16 out. One block (256 thr) per row.
// ---------------------------------------------------------------------------
__device__ __forceinline__ float block_sum256(float v, float* red, int tid) {
#pragma unroll
    for (int m = 32; m >= 1; m >>= 1) v += __shfl_xor(v, m, 64);
    if ((tid & 63) == 0) red[tid >> 6] = v;
    __syncthreads();
    v = red[0] + red[1] + red[2] + red[3];
    __syncthreads();
    return v;
}

__global__ __launch_bounds__(256) void ln_kernel(const float* __restrict__ in,
                                                 const float* __restrict__ scale,
                                                 const float* __restrict__ bias,
                                                 bf16* __restrict__ out) {
    __shared__ float red[4];
    int row = blockIdx.x, tid = threadIdx.x;
    const float* p = in + (size_t)row * C_;
    float v0 = p[tid], v1 = p[tid + 256], v2 = p[tid + 512];
    float mu = block_sum256(v0 + v1 + v2, red, tid) * (1.0f / C_);
    float d0 = v0 - mu, d1 = v1 - mu, d2 = v2 - mu;
    float var = block_sum256(d0 * d0 + d1 * d1 + d2 * d2, red, tid) * (1.0f / C_);
    float rstd = rsqrtf(var + 1e-5f);
    bf16* o = out + (size_t)row * C_;
    o[tid]       = (bf16)(d0 * rstd * scale[tid]       + bias[tid]);
    o[tid + 256] = (bf16)(d1 * rstd * scale[tid + 256] + bias[tid + 256]);
    o[tid + 512] = (bf16)(d2 * rstd * scale[tid + 512] + bias[tid + 512]);
}

// ---------------------------------------------------------------------------
// GEMM: C[M,N] = A[M,K](bf16) * BT[N,K](bf16)^T + bias, fused epilogue.
// 128x128 tile, BK=32, 4 waves (2x2), each wave 64x64 via 4x4 16x16x32 MFMA.
// ---------------------------------------------------------------------------
enum { EPI_BF16 = 0, EPI_RES_F32 = 1, EPI_GELU_BF16 = 2 };

template <int EPI>
__global__ __launch_bounds__(256) void gemm_kernel(
    const bf16* __restrict__ A, const bf16* __restrict__ BT,
    const float* __restrict__ bias, const float* __restrict__ res,
    void* __restrict__ outv, int N, int K) {
    __shared__ bf16 Al[128 * 32];
    __shared__ bf16 Bl[128 * 32];
    const int tid = threadIdx.x;
    const int l = tid & 63, w = tid >> 6;
    const int wm = w >> 1, wn = w & 1;
    const int bm = blockIdx.y * 128, bn = blockIdx.x * 128;
    const int lr = l & 15, lh = l >> 4, d0 = lh * 8;

    f32x4 acc[4][4] = {};

    for (int kt = 0; kt < K; kt += 32) {
        __syncthreads();  // previous-iter LDS reads done before overwrite
#pragma unroll
        for (int c = 0; c < 2; ++c) {
            int i = tid + c * 256;           // 512 chunks of 16B per tile
            int row = i >> 2, seg = i & 3;   // [128 rows][4 x 8 bf16]
            GLOAD_LDS16(A + (size_t)(bm + row) * K + kt + seg * 8, Al + i * 8);
            GLOAD_LDS16(BT + (size_t)(bn + row) * K + kt + seg * 8, Bl + i * 8);
        }
        asm volatile("s_waitcnt vmcnt(0)" ::: "memory");
        __syncthreads();

        bf16x8 af[4], bfr[4];
#pragma unroll
        for (int mt = 0; mt < 4; ++mt)
            af[mt] = *(const bf16x8*)(Al + (wm * 64 + mt * 16 + lr) * 32 + d0);
#pragma unroll
        for (int nt = 0; nt < 4; ++nt)
            bfr[nt] = *(const bf16x8*)(Bl + (wn * 64 + nt * 16 + lr) * 32 + d0);
#pragma unroll
        for (int mt = 0; mt < 4; ++mt)
#pragma unroll
            for (int nt = 0; nt < 4; ++nt)
                acc[mt][nt] = mfma16(af[mt], bfr[nt], acc[mt][nt]);
    }

#pragma unroll
    for (int mt = 0; mt < 4; ++mt) {
#pragma unroll
        for (int nt = 0; nt < 4; ++nt) {
#pragma unroll
            for (int r = 0; r < 4; ++r) {
                int row = bm + wm * 64 + mt * 16 + lh * 4 + r;
                int col = bn + wn * 64 + nt * 16 + lr;
                float v = acc[mt][nt][r] + bias[col];
                if (EPI == EPI_RES_F32) {
                    ((float*)outv)[(size_t)row * N + col] =
                        v + res[(size_t)row * N + col];
                } else if (EPI == EPI_GELU_BF16) {
                    float x4 = v * v * v * v;  // faithful to source: no leading x+
                    float g = 0.5f * v *
                              (1.0f + tanhf(0.7978845608028654f * 0.044715f * x4));
                    ((bf16*)outv)[(size_t)row * N + col] = (bf16)g;
                } else {
                    ((bf16*)outv)[(size_t)row * N + col] = (bf16)v;
                }
            }
        }
    }
}

// ---------------------------------------------------------------------------
// Causal flash attention. qkv bf16 [4096, 2304] (per head: q|k|v of 64 each).
// Block = (qt, h, b), 4 waves x 16 Q-rows. K-chunk 64, online softmax fp32.
// ---------------------------------------------------------------------------
__global__ __launch_bounds__(256) void attn_kernel(const bf16* __restrict__ qkv,
                                                   bf16* __restrict__ y) {
    const int qt = blockIdx.x, h = blockIdx.y, b = blockIdx.z;
    const int tid = threadIdx.x, l = tid & 63, w = tid >> 6;
    const int lr = l & 15, lh = l >> 4, d0 = lh * 8;

    __shared__ bf16 Kl[64 * 64];
    __shared__ bf16 Vt[64 * 64];      // transposed: Vt[d][k]
    __shared__ bf16 Pl[4][16 * 64];   // per-wave P relayout buffer

    const int bc = h * 192;
    const int qrow = qt * 64 + w * 16 + lr;
    const bf16* qp = qkv + (size_t)(b * T_ + qrow) * C3_ + bc;
    bf16x8 qf0 = *(const bf16x8*)(qp + d0);
    bf16x8 qf1 = *(const bf16x8*)(qp + 32 + d0);

    f32x4 acc_o[4] = {};
    float m_run[4], l_run[4];
#pragma unroll
    for (int i = 0; i < 4; ++i) { m_run[i] = -1e30f; l_run[i] = 0.f; }

    for (int kc = 0; kc <= qt; ++kc) {
        __syncthreads();
        for (int i = tid; i < 512; i += 256) {  // stage K and V^T (64x64 each)
            int row = i >> 3, seg = i & 7;
            const bf16* kvp = qkv + (size_t)(b * T_ + kc * 64 + row) * C3_ + bc;
            *(bf16x8*)(Kl + row * 64 + seg * 8) = *(const bf16x8*)(kvp + 64 + seg * 8);
            bf16x8 vv = *(const bf16x8*)(kvp + 128 + seg * 8);
#pragma unroll
            for (int j = 0; j < 8; ++j) Vt[(seg * 8 + j) * 64 + row] = vv[j];
        }
        __syncthreads();

        // S = Q K^T (this wave's 16 rows x 64 cols)
        f32x4 s[4] = {};
#pragma unroll
        for (int nt = 0; nt < 4; ++nt) {
            bf16x8 kb0 = *(const bf16x8*)(Kl + (nt * 16 + lr) * 64 + d0);
            bf16x8 kb1 = *(const bf16x8*)(Kl + (nt * 16 + lr) * 64 + 32 + d0);
            s[nt] = mfma16(qf0, kb0, s[nt]);
            s[nt] = mfma16(qf1, kb1, s[nt]);
        }

        // scale + causal mask + row max
        float ps[4][4], rmax[4];
#pragma unroll
        for (int r = 0; r < 4; ++r) rmax[r] = -1e30f;
#pragma unroll
        for (int nt = 0; nt < 4; ++nt) {
#pragma unroll
            for (int r = 0; r < 4; ++r) {
                float v = s[nt][r] * 0.125f;
                int col = kc * 64 + nt * 16 + lr;
                int rq = qt * 64 + w * 16 + lh * 4 + r;
                if (col > rq) v = -1e30f;
                ps[nt][r] = v;
                rmax[r] = fmaxf(rmax[r], v);
            }
        }
#pragma unroll
        for (int m = 1; m < 16; m <<= 1)
#pragma unroll
            for (int r = 0; r < 4; ++r)
                rmax[r] = fmaxf(rmax[r], __shfl_xor(rmax[r], m, 64));

        float lad[4];
#pragma unroll
        for (int r = 0; r < 4; ++r) {
            float mnew = fmaxf(m_run[r], rmax[r]);
            float sc = __expf(m_run[r] - mnew);
            l_run[r] *= sc;
#pragma unroll
            for (int nt = 0; nt < 4; ++nt) acc_o[nt][r] *= sc;
            m_run[r] = mnew;
            lad[r] = 0.f;
        }
#pragma unroll
        for (int nt = 0; nt < 4; ++nt)
#pragma unroll
            for (int r = 0; r < 4; ++r) {
                float p = __expf(ps[nt][r] - m_run[r]);
                ps[nt][r] = p;
                lad[r] += p;
            }
#pragma unroll
        for (int m = 1; m < 16; m <<= 1)
#pragma unroll
            for (int r = 0; r < 4; ++r) lad[r] += __shfl_xor(lad[r], m, 64);
#pragma unroll
        for (int r = 0; r < 4; ++r) l_run[r] += lad[r];

        // P -> per-wave LDS (relayout S-frag -> A-frag), then PV
#pragma unroll
        for (int nt = 0; nt < 4; ++nt)
#pragma unroll
            for (int r = 0; r < 4; ++r)
                Pl[w][(lh * 4 + r) * 64 + nt * 16 + lr] = (bf16)ps[nt][r];

        bf16x8 pa0 = *(const bf16x8*)(Pl[w] + lr * 64 + d0);
        bf16x8 pa1 = *(const bf16x8*)(Pl[w] + lr * 64 + 32 + d0);
#pragma unroll
        for (int nt = 0; nt < 4; ++nt) {
            bf16x8 vb0 = *(const bf16x8*)(Vt + (nt * 16 + lr) * 64 + d0);
            bf16x8 vb1 = *(const bf16x8*)(Vt + (nt * 16 + lr) * 64 + 32 + d0);
            acc_o[nt] = mfma16(pa0, vb0, acc_o[nt]);
            acc_o[nt] = mfma16(pa1, vb1, acc_o[nt]);
        }
    }

#pragma unroll
    for (int nt = 0; nt < 4; ++nt)
#pragma unroll
        for (int r = 0; r < 4; ++r) {
            int rq = qt * 64 + w * 16 + lh * 4 + r;
            int d = nt * 16 + lr;
            y[(size_t)(b * T_ + rq) * C_ + h * 64 + d] =
                (bf16)(acc_o[nt][r] / l_run[r]);
        }
}

// ---------------------------------------------------------------------------
extern "C" void kernel_launch(void* const* d_in, const int* in_sizes, int n_in,
                              void* d_out, int out_size, void* d_ws, size_t ws_size,
                              hipStream_t stream) {
    (void)in_sizes; (void)n_in; (void)out_size; (void)ws_size;
    const float* x     = (const float*)d_in[0];
    const float* ln1_s = (const float*)d_in[1];
    const float* ln1_b = (const float*)d_in[2];
    const float* Wqkv  = (const float*)d_in[3];
    const float* bqkv  = (const float*)d_in[4];
    const float* Wo    = (const float*)d_in[5];
    const float* bo    = (const float*)d_in[6];
    const float* ln2_s = (const float*)d_in[7];
    const float* ln2_b = (const float*)d_in[8];
    const float* Wfc   = (const float*)d_in[9];
    const float* bfc   = (const float*)d_in[10];
    const float* Wproj = (const float*)d_in[11];
    const float* bproj = (const float*)d_in[12];

    char* ws = (char*)d_ws;
    // lnbuf reused for: xln1 -> attention-out y -> xln2 (each dead before reuse)
    bf16*  lnbuf  = (bf16*)(ws);                      // 4096*768*2  = 6291456
    bf16*  qkv    = (bf16*)(ws + 6291456);            // 4096*2304*2 = 18874368
    float* x2     = (float*)(ws + 25165824);          // 4096*768*4  = 12582912
    bf16*  fcbuf  = (bf16*)(ws + 37748736);           // 4096*3072*2 = 25165824
    bf16*  WqkvT  = (bf16*)(ws + 62914560);           // 2304*768*2  = 3538944
    bf16*  WoT    = (bf16*)(ws + 66453504);           // 768*768*2   = 1179648
    bf16*  WfcT   = (bf16*)(ws + 67633152);           // 3072*768*2  = 4718592
    bf16*  WprojT = (bf16*)(ws + 72351744);           // 768*3072*2  = 4718592
                                                      // total ~77.1 MB

    dim3 tb(32, 8);
    transpose_cast_kernel<<<dim3(C3_ / 32, C_ / 32), tb, 0, stream>>>(Wqkv, WqkvT, C_, C3_);
    transpose_cast_kernel<<<dim3(C_ / 32, C_ / 32), tb, 0, stream>>>(Wo, WoT, C_, C_);
    transpose_cast_kernel<<<dim3(C4_ / 32, C_ / 32), tb, 0, stream>>>(Wfc, WfcT, C_, C4_);
    transpose_cast_kernel<<<dim3(C_ / 32, C4_ / 32), tb, 0, stream>>>(Wproj, WprojT, C4_, C_);

    ln_kernel<<<M_, 256, 0, stream>>>(x, ln1_s, ln1_b, lnbuf);

    gemm_kernel<EPI_BF16><<<dim3(C3_ / 128, M_ / 128), 256, 0, stream>>>(
        lnbuf, WqkvT, bqkv, nullptr, qkv, C3_, C_);

    attn_kernel<<<dim3(T_ / 64, H_, B_), 256, 0, stream>>>(qkv, lnbuf);

    gemm_kernel<EPI_RES_F32><<<dim3(C_ / 128, M_ / 128), 256, 0, stream>>>(
        lnbuf, WoT, bo, x, x2, C_, C_);

    ln_kernel<<<M_, 256, 0, stream>>>(x2, ln2_s, ln2_b, lnbuf);

    gemm_kernel<EPI_GELU_BF16><<<dim3(C4_ / 128, M_ / 128), 256, 0, stream>>>(
        lnbuf, WfcT, bfc, nullptr, fcbuf, C4_, C_);

    gemm_kernel<EPI_RES_F32><<<dim3(C_ / 128, M_ / 128), 256, 0, stream>>>(
        fcbuf, WprojT, bproj, x2, (float*)d_out, C_, C4_);
}

// Round 2
// 229.220 us; speedup vs baseline: 1.1710x; 1.1710x over previous
//
#include <hip/hip_runtime.h>
#include <hip/hip_bf16.h>
#include <math.h>

#define B_  4
#define T_  1024
#define C_  768
#define H_  12
#define HD_ 64
#define M_  (B_*T_)     // 4096 rows
#define C3_ (3*C_)      // 2304
#define C4_ (4*C_)      // 3072

typedef __bf16 bf16;
typedef bf16  bf16x2 __attribute__((ext_vector_type(2)));
typedef bf16  bf16x8 __attribute__((ext_vector_type(8)));
typedef float f32x4  __attribute__((ext_vector_type(4)));

__device__ __forceinline__ f32x4 mfma16(bf16x8 a, bf16x8 b, f32x4 c) {
    return __builtin_amdgcn_mfma_f32_16x16x32_bf16(a, b, c, 0, 0, 0);
}

#define GLOAD_LDS16(g, l)                                                     \
    __builtin_amdgcn_global_load_lds(                                         \
        (const __attribute__((address_space(1))) void*)(g),                   \
        (__attribute__((address_space(3))) void*)(l), 16, 0, 0)

// ---------------------------------------------------------------------------
// Transpose + cast: in fp32 [K,N] -> out bf16 [N,K]
// ---------------------------------------------------------------------------
__global__ void transpose_cast_kernel(const float* __restrict__ in,
                                      bf16* __restrict__ out, int K, int N) {
    __shared__ float tile[32][33];
    int n0 = blockIdx.x * 32, k0 = blockIdx.y * 32;
    int tx = threadIdx.x, ty = threadIdx.y;  // 32 x 8
#pragma unroll
    for (int i = 0; i < 32; i += 8)
        tile[ty + i][tx] = in[(size_t)(k0 + ty + i) * N + n0 + tx];
    __syncthreads();
#pragma unroll
    for (int i = 0; i < 32; i += 8)
        out[(size_t)(n0 + ty + i) * K + k0 + tx] = (bf16)tile[tx][ty + i];
}

// ---------------------------------------------------------------------------
// LayerNorm: fp32 in [rows, 768] -> bf16 out. One block (256 thr) per row.
// ---------------------------------------------------------------------------
__device__ __forceinline__ float block_sum256(float v, float* red, int tid) {
#pragma unroll
    for (int m = 32; m >= 1; m >>= 1) v += __shfl_xor(v, m, 64);
    if ((tid & 63) == 0) red[tid >> 6] = v;
    __syncthreads();
    v = red[0] + red[1] + red[2] + red[3];
    __syncthreads();
    return v;
}

__global__ __launch_bounds__(256) void ln_kernel(const float* __restrict__ in,
                                                 const float* __restrict__ scale,
                                                 const float* __restrict__ bias,
                                                 bf16* __restrict__ out) {
    __shared__ float red[4];
    int row = blockIdx.x, tid = threadIdx.x;
    const float* p = in + (size_t)row * C_;
    float v0 = p[tid], v1 = p[tid + 256], v2 = p[tid + 512];
    float mu = block_sum256(v0 + v1 + v2, red, tid) * (1.0f / C_);
    float d0 = v0 - mu, d1 = v1 - mu, d2 = v2 - mu;
    float var = block_sum256(d0 * d0 + d1 * d1 + d2 * d2, red, tid) * (1.0f / C_);
    float rstd = rsqrtf(var + 1e-5f);
    bf16* o = out + (size_t)row * C_;
    o[tid]       = (bf16)(d0 * rstd * scale[tid]       + bias[tid]);
    o[tid + 256] = (bf16)(d1 * rstd * scale[tid + 256] + bias[tid + 256]);
    o[tid + 512] = (bf16)(d2 * rstd * scale[tid + 512] + bias[tid + 512]);
}

// ---------------------------------------------------------------------------
// GEMM: C[M,N] = A[M,K](bf16) * BT[N,K](bf16)^T + bias, fused epilogue.
// 128x128 tile, BK=32, 4 waves (2x2), each wave 64x64 via 4x4 16x16x32 MFMA.
// ---------------------------------------------------------------------------
enum { EPI_BF16 = 0, EPI_RES_F32 = 1, EPI_GELU_BF16 = 2 };

template <int EPI>
__global__ __launch_bounds__(256) void gemm_kernel(
    const bf16* __restrict__ A, const bf16* __restrict__ BT,
    const float* __restrict__ bias, const float* __restrict__ res,
    void* __restrict__ outv, int N, int K) {
    __shared__ bf16 Al[128 * 32];
    __shared__ bf16 Bl[128 * 32];
    const int tid = threadIdx.x;
    const int l = tid & 63, w = tid >> 6;
    const int wm = w >> 1, wn = w & 1;
    const int bm = blockIdx.y * 128, bn = blockIdx.x * 128;
    const int lr = l & 15, lh = l >> 4, d0 = lh * 8;

    f32x4 acc[4][4] = {};

    for (int kt = 0; kt < K; kt += 32) {
        __syncthreads();
#pragma unroll
        for (int c = 0; c < 2; ++c) {
            int i = tid + c * 256;
            int row = i >> 2, seg = i & 3;
            GLOAD_LDS16(A + (size_t)(bm + row) * K + kt + seg * 8, Al + i * 8);
            GLOAD_LDS16(BT + (size_t)(bn + row) * K + kt + seg * 8, Bl + i * 8);
        }
        asm volatile("s_waitcnt vmcnt(0)" ::: "memory");
        __syncthreads();

        bf16x8 af[4], bfr[4];
#pragma unroll
        for (int mt = 0; mt < 4; ++mt)
            af[mt] = *(const bf16x8*)(Al + (wm * 64 + mt * 16 + lr) * 32 + d0);
#pragma unroll
        for (int nt = 0; nt < 4; ++nt)
            bfr[nt] = *(const bf16x8*)(Bl + (wn * 64 + nt * 16 + lr) * 32 + d0);
#pragma unroll
        for (int mt = 0; mt < 4; ++mt)
#pragma unroll
            for (int nt = 0; nt < 4; ++nt)
                acc[mt][nt] = mfma16(af[mt], bfr[nt], acc[mt][nt]);
    }

#pragma unroll
    for (int mt = 0; mt < 4; ++mt) {
#pragma unroll
        for (int nt = 0; nt < 4; ++nt) {
#pragma unroll
            for (int r = 0; r < 4; ++r) {
                int row = bm + wm * 64 + mt * 16 + lh * 4 + r;
                int col = bn + wn * 64 + nt * 16 + lr;
                float v = acc[mt][nt][r] + bias[col];
                if (EPI == EPI_RES_F32) {
                    ((float*)outv)[(size_t)row * N + col] =
                        v + res[(size_t)row * N + col];
                } else if (EPI == EPI_GELU_BF16) {
                    float x4 = v * v * v * v;  // faithful to source: no leading x+
                    float g = 0.5f * v *
                              (1.0f + tanhf(0.7978845608028654f * 0.044715f * x4));
                    ((bf16*)outv)[(size_t)row * N + col] = (bf16)g;
                } else {
                    ((bf16*)outv)[(size_t)row * N + col] = (bf16)v;
                }
            }
        }
    }
}

// ---------------------------------------------------------------------------
// V pre-transpose: qkv V-part [t][d] per head -> vt[(b*H+h)][d=64][T=1024]
// 64x64 tiles, XOR-swizzled LDS, fully coalesced both sides.
// ---------------------------------------------------------------------------
__global__ __launch_bounds__(256) void vtrans_kernel(const bf16* __restrict__ qkv,
                                                     bf16* __restrict__ vt) {
    __shared__ bf16 tl[64 * 64];
    const int tid = threadIdx.x;
    const int t0 = blockIdx.x * 64;
    const int hv = blockIdx.y;          // b*H + h
    const int b = hv / H_, h = hv % H_;
    const int src0 = h * 192 + 128;
#pragma unroll
    for (int c = 0; c < 2; ++c) {
        int i = tid + c * 256;
        int row = i >> 3, seg = i & 7;  // row = t-within-tile
        bf16x8 v = *(const bf16x8*)(qkv + (size_t)(b * T_ + t0 + row) * C3_ +
                                    src0 + seg * 8);
        *(bf16x8*)(tl + row * 64 + ((seg ^ (row & 7)) * 8)) = v;
    }
    __syncthreads();
#pragma unroll
    for (int c = 0; c < 2; ++c) {
        int i = tid + c * 256;
        int d = i >> 3, ts = i & 7;
        bf16x8 o;
#pragma unroll
        for (int j = 0; j < 8; ++j)
            o[j] = tl[(ts * 8 + j) * 64 + (d ^ (j * 8))];
        *(bf16x8*)(vt + (size_t)(hv * 64 + d) * T_ + t0 + ts * 8) = o;
    }
}

// ---------------------------------------------------------------------------
// Causal flash attention, swapped-QK^T, double-buffered swizzled K/V staging.
// Flat grid 768: XCD-grouped so one (b,h)'s 16 q-tiles share an XCD's L2.
// 4 waves x 16 q-rows, KVBLK=64. Softmax per-lane (lane owns q-row = lr).
// ---------------------------------------------------------------------------
__global__ __launch_bounds__(256) void attn_kernel(const bf16* __restrict__ qkv,
                                                   const bf16* __restrict__ vt,
                                                   bf16* __restrict__ y) {
    // flat -> (qt, h, b): flat%8 selects XCD group; 6 (b,h) groups per XCD
    const int flat = blockIdx.x;
    const int g = (flat & 7) * 6 + (flat >> 3) / 16;  // 0..47 = b*H+h
    const int qt = (flat >> 3) & 15;
    const int h = g % H_, b = g / H_, hv = g;

    const int tid = threadIdx.x, l = tid & 63, w = tid >> 6;
    const int lr = l & 15, lh = l >> 4, d0 = lh * 8;
    const int bc = h * 192;

    __shared__ bf16 Kl[2][64 * 64];
    __shared__ bf16 Vl[2][64 * 64];
    __shared__ bf16 Pl[4][16 * 64];

    // Q fragment (b-operand: rows of Q), q-row = qt*64 + w*16 + lr
    const int qg = qt * 64 + w * 16 + lr;
    const bf16* qp = qkv + (size_t)(b * T_ + qg) * C3_ + bc;
    bf16x8 qf0 = *(const bf16x8*)(qp + d0);
    bf16x8 qf1 = *(const bf16x8*)(qp + 32 + d0);

#define ATTN_STAGE(buf, kc)                                                     \
    {                                                                           \
        _Pragma("unroll")                                                       \
        for (int c = 0; c < 2; ++c) {                                           \
            int i = tid + c * 256;                                              \
            int row = i >> 3, seg = i & 7, ss = seg ^ (row & 7);                \
            GLOAD_LDS16(qkv + (size_t)(b * T_ + (kc) * 64 + row) * C3_ + bc +   \
                            64 + ss * 8,                                        \
                        &Kl[buf][i * 8]);                                       \
            GLOAD_LDS16(vt + (size_t)(hv * 64 + row) * T_ + (kc) * 64 + ss * 8, \
                        &Vl[buf][i * 8]);                                       \
        }                                                                       \
    }

    f32x4 acc_o[4] = {};
    float m_run = -1e30f, l_run = 0.f;
    const float SCL = 0.125f * 1.44269504089f;  // 1/sqrt(HD) * log2(e)

    ATTN_STAGE(0, 0);

    for (int kc = 0; kc <= qt; ++kc) {
        const int cur = kc & 1;
        if (kc < qt) {
            ATTN_STAGE(cur ^ 1, kc + 1);
            asm volatile("s_waitcnt vmcnt(4)" ::: "memory");
        } else {
            asm volatile("s_waitcnt vmcnt(0)" ::: "memory");
        }
        __syncthreads();

        const bf16* Kb = Kl[cur];
        const bf16* Vb = Vl[cur];

        // S^T = K Q^T : lane holds S[k = kc*64+nt*16+lh*4+r][q = qg]
        f32x4 st[4];
#pragma unroll
        for (int nt = 0; nt < 4; ++nt) {
            int R = nt * 16 + lr;
            const bf16* kb = Kb + R * 64;
            bf16x8 k0 = *(const bf16x8*)(kb + (lh ^ (R & 7)) * 8);
            bf16x8 k1 = *(const bf16x8*)(kb + ((4 + lh) ^ (R & 7)) * 8);
            f32x4 a = {};
            a = mfma16(k0, qf0, a);
            st[nt] = mfma16(k1, qf1, a);
        }

        // softmax in log2 domain; lane owns q-row qg, 16 k-values
        const int diag = (kc == qt);
        float p[16], pmax = -1e30f;
#pragma unroll
        for (int nt = 0; nt < 4; ++nt)
#pragma unroll
            for (int r = 0; r < 4; ++r) {
                float v = st[nt][r] * SCL;
                if (diag) {
                    int kg = kc * 64 + nt * 16 + lh * 4 + r;
                    if (kg > qg) v = -1e38f;
                }
                p[nt * 4 + r] = v;
                pmax = fmaxf(pmax, v);
            }
        pmax = fmaxf(pmax, __shfl_xor(pmax, 16, 64));
        pmax = fmaxf(pmax, __shfl_xor(pmax, 32, 64));

        if (!__all(pmax - m_run <= 8.0f)) {  // defer-max (T13), THR=8 (log2)
            float mnew = fmaxf(m_run, pmax);
            float sc = exp2f(m_run - mnew);
            l_run *= sc;
            m_run = mnew;
#pragma unroll
            for (int r = 0; r < 4; ++r) {
                float sq = __shfl(sc, lh * 4 + r, 64);
#pragma unroll
                for (int nt = 0; nt < 4; ++nt) acc_o[nt][r] *= sq;
            }
        }

        float lsum = 0.f;
#pragma unroll
        for (int i = 0; i < 16; ++i) {
            p[i] = exp2f(p[i] - m_run);
            lsum += p[i];
        }
        lsum += __shfl_xor(lsum, 16, 64);
        lsum += __shfl_xor(lsum, 32, 64);
        l_run += lsum;

        // P -> Pl[q_local = lr][k], swizzled rows (write pairs: k even/odd)
        {
            char* pw = (char*)&Pl[w][0];
            int swz = (lr & 7) << 4;
#pragma unroll
            for (int nt = 0; nt < 4; ++nt)
#pragma unroll
                for (int rr = 0; rr < 2; ++rr) {
                    int kk = nt * 16 + lh * 4 + rr * 2;
                    bf16x2 pr = {(bf16)p[nt * 4 + rr * 2],
                                 (bf16)p[nt * 4 + rr * 2 + 1]};
                    *(bf16x2*)(pw + lr * 128 + ((kk * 2) ^ swz)) = pr;
                }
        }

        // PV: a-frag = Pl rows (q_local), b-frag = Vl rows (d)
        {
            const bf16* pb = &Pl[w][0] + lr * 64;
            bf16x8 pa0 = *(const bf16x8*)(pb + (lh ^ (lr & 7)) * 8);
            bf16x8 pa1 = *(const bf16x8*)(pb + ((4 + lh) ^ (lr & 7)) * 8);
#pragma unroll
            for (int nt = 0; nt < 4; ++nt) {
                int R = nt * 16 + lr;
                const bf16* vb = Vb + R * 64;
                bf16x8 v0 = *(const bf16x8*)(vb + (lh ^ (R & 7)) * 8);
                bf16x8 v1 = *(const bf16x8*)(vb + ((4 + lh) ^ (R & 7)) * 8);
                acc_o[nt] = mfma16(pa0, v0, acc_o[nt]);
                acc_o[nt] = mfma16(pa1, v1, acc_o[nt]);
            }
        }
        __syncthreads();
    }

    // output: O[q = qt*64+w*16+lh*4+r][d = nt*16+lr], normalize by 1/l(q)
    float rl = 1.0f / l_run;
#pragma unroll
    for (int r = 0; r < 4; ++r) {
        float rq = __shfl(rl, lh * 4 + r, 64);
        int q = qt * 64 + w * 16 + lh * 4 + r;
#pragma unroll
        for (int nt = 0; nt < 4; ++nt)
            y[(size_t)(b * T_ + q) * C_ + h * 64 + nt * 16 + lr] =
                (bf16)(acc_o[nt][r] * rq);
    }
#undef ATTN_STAGE
}

// ---------------------------------------------------------------------------
extern "C" void kernel_launch(void* const* d_in, const int* in_sizes, int n_in,
                              void* d_out, int out_size, void* d_ws, size_t ws_size,
                              hipStream_t stream) {
    (void)in_sizes; (void)n_in; (void)out_size; (void)ws_size;
    const float* x     = (const float*)d_in[0];
    const float* ln1_s = (const float*)d_in[1];
    const float* ln1_b = (const float*)d_in[2];
    const float* Wqkv  = (const float*)d_in[3];
    const float* bqkv  = (const float*)d_in[4];
    const float* Wo    = (const float*)d_in[5];
    const float* bo    = (const float*)d_in[6];
    const float* ln2_s = (const float*)d_in[7];
    const float* ln2_b = (const float*)d_in[8];
    const float* Wfc   = (const float*)d_in[9];
    const float* bfc   = (const float*)d_in[10];
    const float* Wproj = (const float*)d_in[11];
    const float* bproj = (const float*)d_in[12];

    char* ws = (char*)d_ws;
    // lnbuf reused for: xln1 -> attention-out y -> xln2 (each dead before reuse)
    bf16*  lnbuf  = (bf16*)(ws);                      // 4096*768*2  = 6291456
    bf16*  qkv    = (bf16*)(ws + 6291456);            // 4096*2304*2 = 18874368
    float* x2     = (float*)(ws + 25165824);          // 4096*768*4  = 12582912
    bf16*  fcbuf  = (bf16*)(ws + 37748736);           // 4096*3072*2 = 25165824
    // vt overlaps fcbuf: vt live [vtrans, attn], fcbuf live [fc-gemm, proj-gemm]
    bf16*  vtbuf  = (bf16*)(ws + 37748736);           // 48*64*1024*2 = 6291456
    bf16*  WqkvT  = (bf16*)(ws + 62914560);           // 2304*768*2  = 3538944
    bf16*  WoT    = (bf16*)(ws + 66453504);           // 768*768*2   = 1179648
    bf16*  WfcT   = (bf16*)(ws + 67633152);           // 3072*768*2  = 4718592
    bf16*  WprojT = (bf16*)(ws + 72351744);           // 768*3072*2  = 4718592

    dim3 tb(32, 8);
    transpose_cast_kernel<<<dim3(C3_ / 32, C_ / 32), tb, 0, stream>>>(Wqkv, WqkvT, C_, C3_);
    transpose_cast_kernel<<<dim3(C_ / 32, C_ / 32), tb, 0, stream>>>(Wo, WoT, C_, C_);
    transpose_cast_kernel<<<dim3(C4_ / 32, C_ / 32), tb, 0, stream>>>(Wfc, WfcT, C_, C4_);
    transpose_cast_kernel<<<dim3(C_ / 32, C4_ / 32), tb, 0, stream>>>(Wproj, WprojT, C4_, C_);

    ln_kernel<<<M_, 256, 0, stream>>>(x, ln1_s, ln1_b, lnbuf);

    gemm_kernel<EPI_BF16><<<dim3(C3_ / 128, M_ / 128), 256, 0, stream>>>(
        lnbuf, WqkvT, bqkv, nullptr, qkv, C3_, C_);

    vtrans_kernel<<<dim3(T_ / 64, B_ * H_), 256, 0, stream>>>(qkv, vtbuf);

    attn_kernel<<<dim3(768), 256, 0, stream>>>(qkv, vtbuf, lnbuf);

    gemm_kernel<EPI_RES_F32><<<dim3(C_ / 128, M_ / 128), 256, 0, stream>>>(
        lnbuf, WoT, bo, x, x2, C_, C_);

    ln_kernel<<<M_, 256, 0, stream>>>(x2, ln2_s, ln2_b, lnbuf);

    gemm_kernel<EPI_GELU_BF16><<<dim3(C4_ / 128, M_ / 128), 256, 0, stream>>>(
        lnbuf, WfcT, bfc, nullptr, fcbuf, C4_, C_);

    gemm_kernel<EPI_RES_F32><<<dim3(C_ / 128, M_ / 128), 256, 0, stream>>>(
        fcbuf, WprojT, bproj, x2, (float*)d_out, C_, C4_);
}

// Round 3
// 192.080 us; speedup vs baseline: 1.3974x; 1.1934x over previous
//
#include <hip/hip_runtime.h>
#include <hip/hip_bf16.h>
#include <math.h>

#define B_  4
#define T_  1024
#define C_  768
#define H_  12
#define HD_ 64
#define M_  (B_*T_)     // 4096 rows
#define C3_ (3*C_)      // 2304
#define C4_ (4*C_)      // 3072

typedef __bf16 bf16;
typedef bf16  bf16x2 __attribute__((ext_vector_type(2)));
typedef bf16  bf16x8 __attribute__((ext_vector_type(8)));
typedef float f32x4  __attribute__((ext_vector_type(4)));

__device__ __forceinline__ f32x4 mfma16(bf16x8 a, bf16x8 b, f32x4 c) {
    return __builtin_amdgcn_mfma_f32_16x16x32_bf16(a, b, c, 0, 0, 0);
}

#define GLOAD_LDS16(g, l)                                                     \
    __builtin_amdgcn_global_load_lds(                                         \
        (const __attribute__((address_space(1))) void*)(g),                   \
        (__attribute__((address_space(3))) void*)(l), 16, 0, 0)

// ---------------------------------------------------------------------------
// Transpose + cast: in fp32 [K,N] -> out bf16 [N,K]
// ---------------------------------------------------------------------------
__global__ void transpose_cast_kernel(const float* __restrict__ in,
                                      bf16* __restrict__ out, int K, int N) {
    __shared__ float tile[32][33];
    int n0 = blockIdx.x * 32, k0 = blockIdx.y * 32;
    int tx = threadIdx.x, ty = threadIdx.y;  // 32 x 8
#pragma unroll
    for (int i = 0; i < 32; i += 8)
        tile[ty + i][tx] = in[(size_t)(k0 + ty + i) * N + n0 + tx];
    __syncthreads();
#pragma unroll
    for (int i = 0; i < 32; i += 8)
        out[(size_t)(n0 + ty + i) * K + k0 + tx] = (bf16)tile[tx][ty + i];
}

// ---------------------------------------------------------------------------
// LayerNorm: fp32 in [rows, 768] -> bf16 out. One block (256 thr) per row.
// ---------------------------------------------------------------------------
__device__ __forceinline__ float block_sum256(float v, float* red, int tid) {
#pragma unroll
    for (int m = 32; m >= 1; m >>= 1) v += __shfl_xor(v, m, 64);
    if ((tid & 63) == 0) red[tid >> 6] = v;
    __syncthreads();
    v = red[0] + red[1] + red[2] + red[3];
    __syncthreads();
    return v;
}

__global__ __launch_bounds__(256) void ln_kernel(const float* __restrict__ in,
                                                 const float* __restrict__ scale,
                                                 const float* __restrict__ bias,
                                                 bf16* __restrict__ out) {
    __shared__ float red[4];
    int row = blockIdx.x, tid = threadIdx.x;
    const float* p = in + (size_t)row * C_;
    float v0 = p[tid], v1 = p[tid + 256], v2 = p[tid + 512];
    float mu = block_sum256(v0 + v1 + v2, red, tid) * (1.0f / C_);
    float d0 = v0 - mu, d1 = v1 - mu, d2 = v2 - mu;
    float var = block_sum256(d0 * d0 + d1 * d1 + d2 * d2, red, tid) * (1.0f / C_);
    float rstd = rsqrtf(var + 1e-5f);
    bf16* o = out + (size_t)row * C_;
    o[tid]       = (bf16)(d0 * rstd * scale[tid]       + bias[tid]);
    o[tid + 256] = (bf16)(d1 * rstd * scale[tid + 256] + bias[tid + 256]);
    o[tid + 512] = (bf16)(d2 * rstd * scale[tid + 512] + bias[tid + 512]);
}

// ---------------------------------------------------------------------------
// GEMM: C[M,N] = A[M,K] * BT[N,K]^T (+bias/epilogue). 128x128 tile, BK=32,
// double-buffered LDS, issue-early staging, single barrier per K-step.
// Grid: (nx*ny flat XCD-chunked, nsplit). EPI_PARTIAL writes fp32 partials.
// ---------------------------------------------------------------------------
enum { EPI_BF16 = 0, EPI_RES_F32 = 1, EPI_GELU_BF16 = 2, EPI_PARTIAL = 3 };

template <int EPI>
__global__ __launch_bounds__(256) void gemm_kernel(
    const bf16* __restrict__ A, const bf16* __restrict__ BT,
    const float* __restrict__ bias, const float* __restrict__ res,
    void* __restrict__ outv, int N, int Ktot, int nx) {
    __shared__ bf16 Al[2][128 * 32];
    __shared__ bf16 Bl[2][128 * 32];
    const int tid = threadIdx.x;
    const int l = tid & 63, w = tid >> 6;
    const int wm = w >> 1, wn = w & 1;
    // bijective XCD-chunked swizzle (gridDim.x divisible by 8)
    const int cpx = gridDim.x >> 3;
    const int wg = (blockIdx.x & 7) * cpx + (blockIdx.x >> 3);
    const int bm = (wg / nx) * 128, bn = (wg % nx) * 128;
    const int Kper = Ktot / gridDim.y;
    const int k0 = blockIdx.y * Kper;
    const int lr = l & 15, lh = l >> 4, d0 = lh * 8;

#define GEMM_STAGE(buf, kt)                                                    \
    {                                                                          \
        _Pragma("unroll") for (int c = 0; c < 2; ++c) {                        \
            int i = tid + c * 256;                                             \
            int row = i >> 2, seg = i & 3;                                     \
            GLOAD_LDS16(A + (size_t)(bm + row) * Ktot + k0 + (kt) + seg * 8,   \
                        &Al[buf][i * 8]);                                      \
            GLOAD_LDS16(BT + (size_t)(bn + row) * Ktot + k0 + (kt) + seg * 8,  \
                        &Bl[buf][i * 8]);                                      \
        }                                                                      \
    }

    f32x4 acc[4][4] = {};
    const int nk = Kper >> 5;

    GEMM_STAGE(0, 0);
    __syncthreads();  // drain prologue stage

    for (int t = 0; t < nk; ++t) {
        const int cur = t & 1;
        if (t + 1 < nk) GEMM_STAGE(cur ^ 1, (t + 1) * 32);  // issue-early

        bf16x8 af[4], bfr[4];
#pragma unroll
        for (int mt = 0; mt < 4; ++mt)
            af[mt] = *(const bf16x8*)(&Al[cur][(wm * 64 + mt * 16 + lr) * 32 + d0]);
#pragma unroll
        for (int nt = 0; nt < 4; ++nt)
            bfr[nt] = *(const bf16x8*)(&Bl[cur][(wn * 64 + nt * 16 + lr) * 32 + d0]);
#pragma unroll
        for (int mt = 0; mt < 4; ++mt)
#pragma unroll
            for (int nt = 0; nt < 4; ++nt)
                acc[mt][nt] = mfma16(af[mt], bfr[nt], acc[mt][nt]);

        __syncthreads();  // drains next-stage vmem + protects buffer reuse
    }
#undef GEMM_STAGE

#pragma unroll
    for (int mt = 0; mt < 4; ++mt) {
#pragma unroll
        for (int nt = 0; nt < 4; ++nt) {
#pragma unroll
            for (int r = 0; r < 4; ++r) {
                int row = bm + wm * 64 + mt * 16 + lh * 4 + r;
                int col = bn + wn * 64 + nt * 16 + lr;
                if (EPI == EPI_PARTIAL) {
                    ((float*)outv)[(size_t)blockIdx.y * M_ * N +
                                   (size_t)row * N + col] = acc[mt][nt][r];
                } else {
                    float v = acc[mt][nt][r] + bias[col];
                    if (EPI == EPI_RES_F32) {
                        ((float*)outv)[(size_t)row * N + col] =
                            v + res[(size_t)row * N + col];
                    } else if (EPI == EPI_GELU_BF16) {
                        float x4 = v * v * v * v;  // faithful: no leading x+
                        float g = 0.5f * v *
                                  (1.0f + tanhf(0.7978845608028654f * 0.044715f * x4));
                        ((bf16*)outv)[(size_t)row * N + col] = (bf16)g;
                    } else {
                        ((bf16*)outv)[(size_t)row * N + col] = (bf16)v;
                    }
                }
            }
        }
    }
}

// ---------------------------------------------------------------------------
// Split-K=2 reduce: out = part0 + part1 + bias + res   (fp32, float4)
// ---------------------------------------------------------------------------
__global__ __launch_bounds__(256) void reduce2_kernel(const float* __restrict__ part,
                                                      const float* __restrict__ bias,
                                                      const float* __restrict__ res,
                                                      float* __restrict__ out) {
    const size_t MN = (size_t)M_ * C_;
    size_t i = ((size_t)blockIdx.x * 256 + threadIdx.x) * 4;
    if (i >= MN) return;
    f32x4 a = *(const f32x4*)(part + i);
    f32x4 b = *(const f32x4*)(part + MN + i);
    f32x4 r = *(const f32x4*)(res + i);
    f32x4 bi = *(const f32x4*)(bias + (int)(i % C_));
    *(f32x4*)(out + i) = a + b + r + bi;
}

// ---------------------------------------------------------------------------
// V pre-transpose: qkv V-part [t][d] per head -> vt[(b*H+h)][d=64][T=1024]
// ---------------------------------------------------------------------------
__global__ __launch_bounds__(256) void vtrans_kernel(const bf16* __restrict__ qkv,
                                                     bf16* __restrict__ vt) {
    __shared__ bf16 tl[64 * 64];
    const int tid = threadIdx.x;
    const int t0 = blockIdx.x * 64;
    const int hv = blockIdx.y;          // b*H + h
    const int b = hv / H_, h = hv % H_;
    const int src0 = h * 192 + 128;
#pragma unroll
    for (int c = 0; c < 2; ++c) {
        int i = tid + c * 256;
        int row = i >> 3, seg = i & 7;  // row = t-within-tile
        bf16x8 v = *(const bf16x8*)(qkv + (size_t)(b * T_ + t0 + row) * C3_ +
                                    src0 + seg * 8);
        *(bf16x8*)(tl + row * 64 + ((seg ^ (row & 7)) * 8)) = v;
    }
    __syncthreads();
#pragma unroll
    for (int c = 0; c < 2; ++c) {
        int i = tid + c * 256;
        int d = i >> 3, ts = i & 7;
        bf16x8 o;
#pragma unroll
        for (int j = 0; j < 8; ++j)
            o[j] = tl[(ts * 8 + j) * 64 + (d ^ (j * 8))];
        *(bf16x8*)(vt + (size_t)(hv * 64 + d) * T_ + t0 + ts * 8) = o;
    }
}

// ---------------------------------------------------------------------------
// Causal flash attention, swapped-QK^T, double-buffered swizzled K/V staging,
// issue-early single-barrier loop. Grid 768 flat, XCD-grouped per (b,h).
// ---------------------------------------------------------------------------
__global__ __launch_bounds__(256) void attn_kernel(const bf16* __restrict__ qkv,
                                                   const bf16* __restrict__ vt,
                                                   bf16* __restrict__ y) {
    const int flat = blockIdx.x;
    const int g = (flat & 7) * 6 + (flat >> 3) / 16;  // 0..47 = b*H+h
    const int qt = (flat >> 3) & 15;
    const int h = g % H_, b = g / H_, hv = g;

    const int tid = threadIdx.x, l = tid & 63, w = tid >> 6;
    const int lr = l & 15, lh = l >> 4, d0 = lh * 8;
    const int bc = h * 192;

    __shared__ bf16 Kl[2][64 * 64];
    __shared__ bf16 Vl[2][64 * 64];
    __shared__ bf16 Pl[4][16 * 64];

    const int qg = qt * 64 + w * 16 + lr;
    const bf16* qp = qkv + (size_t)(b * T_ + qg) * C3_ + bc;
    bf16x8 qf0 = *(const bf16x8*)(qp + d0);
    bf16x8 qf1 = *(const bf16x8*)(qp + 32 + d0);

#define ATTN_STAGE(buf, kc)                                                     \
    {                                                                           \
        _Pragma("unroll")                                                       \
        for (int c = 0; c < 2; ++c) {                                           \
            int i = tid + c * 256;                                              \
            int row = i >> 3, seg = i & 7, ss = seg ^ (row & 7);                \
            GLOAD_LDS16(qkv + (size_t)(b * T_ + (kc) * 64 + row) * C3_ + bc +   \
                            64 + ss * 8,                                        \
                        &Kl[buf][i * 8]);                                       \
            GLOAD_LDS16(vt + (size_t)(hv * 64 + row) * T_ + (kc) * 64 + ss * 8, \
                        &Vl[buf][i * 8]);                                       \
        }                                                                       \
    }

    f32x4 acc_o[4] = {};
    float m_run = -1e30f, l_run = 0.f;
    const float SCL = 0.125f * 1.44269504089f;  // 1/sqrt(HD) * log2(e)

    ATTN_STAGE(0, 0);
    __syncthreads();  // drain prologue stage

    for (int kc = 0; kc <= qt; ++kc) {
        const int cur = kc & 1;
        if (kc < qt) ATTN_STAGE(cur ^ 1, kc + 1);  // issue-early

        const bf16* Kb = Kl[cur];
        const bf16* Vb = Vl[cur];

        // S^T = K Q^T : lane holds S[k = kc*64+nt*16+lh*4+r][q = qg]
        f32x4 st[4];
#pragma unroll
        for (int nt = 0; nt < 4; ++nt) {
            int R = nt * 16 + lr;
            const bf16* kb = Kb + R * 64;
            bf16x8 k0 = *(const bf16x8*)(kb + (lh ^ (R & 7)) * 8);
            bf16x8 k1 = *(const bf16x8*)(kb + ((4 + lh) ^ (R & 7)) * 8);
            f32x4 a = {};
            a = mfma16(k0, qf0, a);
            st[nt] = mfma16(k1, qf1, a);
        }

        // softmax in log2 domain; lane owns q-row qg, 16 k-values
        const int diag = (kc == qt);
        float p[16], pmax = -1e30f;
#pragma unroll
        for (int nt = 0; nt < 4; ++nt)
#pragma unroll
            for (int r = 0; r < 4; ++r) {
                float v = st[nt][r] * SCL;
                if (diag) {
                    int kg = kc * 64 + nt * 16 + lh * 4 + r;
                    if (kg > qg) v = -1e38f;
                }
                p[nt * 4 + r] = v;
                pmax = fmaxf(pmax, v);
            }
        pmax = fmaxf(pmax, __shfl_xor(pmax, 16, 64));
        pmax = fmaxf(pmax, __shfl_xor(pmax, 32, 64));

        if (!__all(pmax - m_run <= 8.0f)) {  // defer-max (T13), THR=8 (log2)
            float mnew = fmaxf(m_run, pmax);
            float sc = exp2f(m_run - mnew);
            l_run *= sc;
            m_run = mnew;
#pragma unroll
            for (int r = 0; r < 4; ++r) {
                float sq = __shfl(sc, lh * 4 + r, 64);
#pragma unroll
                for (int nt = 0; nt < 4; ++nt) acc_o[nt][r] *= sq;
            }
        }

        float lsum = 0.f;
#pragma unroll
        for (int i = 0; i < 16; ++i) {
            p[i] = exp2f(p[i] - m_run);
            lsum += p[i];
        }
        lsum += __shfl_xor(lsum, 16, 64);
        lsum += __shfl_xor(lsum, 32, 64);
        l_run += lsum;

        // P -> Pl[q_local = lr][k], swizzled rows
        {
            char* pw = (char*)&Pl[w][0];
            int swz = (lr & 7) << 4;
#pragma unroll
            for (int nt = 0; nt < 4; ++nt)
#pragma unroll
                for (int rr = 0; rr < 2; ++rr) {
                    int kk = nt * 16 + lh * 4 + rr * 2;
                    bf16x2 pr = {(bf16)p[nt * 4 + rr * 2],
                                 (bf16)p[nt * 4 + rr * 2 + 1]};
                    *(bf16x2*)(pw + lr * 128 + ((kk * 2) ^ swz)) = pr;
                }
        }

        // PV: a-frag = Pl rows (q_local), b-frag = Vl rows (d)
        {
            const bf16* pb = &Pl[w][0] + lr * 64;
            bf16x8 pa0 = *(const bf16x8*)(pb + (lh ^ (lr & 7)) * 8);
            bf16x8 pa1 = *(const bf16x8*)(pb + ((4 + lh) ^ (lr & 7)) * 8);
#pragma unroll
            for (int nt = 0; nt < 4; ++nt) {
                int R = nt * 16 + lr;
                const bf16* vb = Vb + R * 64;
                bf16x8 v0 = *(const bf16x8*)(vb + (lh ^ (R & 7)) * 8);
                bf16x8 v1 = *(const bf16x8*)(vb + ((4 + lh) ^ (R & 7)) * 8);
                acc_o[nt] = mfma16(pa0, v0, acc_o[nt]);
                acc_o[nt] = mfma16(pa1, v1, acc_o[nt]);
            }
        }
        __syncthreads();  // drains next-stage vmem + protects buffer reuse
    }

    float rl = 1.0f / l_run;
#pragma unroll
    for (int r = 0; r < 4; ++r) {
        float rq = __shfl(rl, lh * 4 + r, 64);
        int q = qt * 64 + w * 16 + lh * 4 + r;
#pragma unroll
        for (int nt = 0; nt < 4; ++nt)
            y[(size_t)(b * T_ + q) * C_ + h * 64 + nt * 16 + lr] =
                (bf16)(acc_o[nt][r] * rq);
    }
#undef ATTN_STAGE
}

// ---------------------------------------------------------------------------
extern "C" void kernel_launch(void* const* d_in, const int* in_sizes, int n_in,
                              void* d_out, int out_size, void* d_ws, size_t ws_size,
                              hipStream_t stream) {
    (void)in_sizes; (void)n_in; (void)out_size; (void)ws_size;
    const float* x     = (const float*)d_in[0];
    const float* ln1_s = (const float*)d_in[1];
    const float* ln1_b = (const float*)d_in[2];
    const float* Wqkv  = (const float*)d_in[3];
    const float* bqkv  = (const float*)d_in[4];
    const float* Wo    = (const float*)d_in[5];
    const float* bo    = (const float*)d_in[6];
    const float* ln2_s = (const float*)d_in[7];
    const float* ln2_b = (const float*)d_in[8];
    const float* Wfc   = (const float*)d_in[9];
    const float* bfc   = (const float*)d_in[10];
    const float* Wproj = (const float*)d_in[11];
    const float* bproj = (const float*)d_in[12];

    char* ws = (char*)d_ws;
    // Layout (77.07 MB total, same as before):
    //   [0, 12.58M)      x2 (fp32 residual); vtbuf aliases [0, 6.29M) (dead before x2 written)
    //   [12.58, 37.75M)  fcbuf
    //   [37.75, 42.47M)  WprojT
    //   [42.47, 48.76M)  lnbuf            } pool: dead at proj time ->
    //   [48.76, 67.63M)  qkv              }   proj partials (2 x 12.58M fp32)
    //   [67.63, 71.17M)  WqkvT
    //   [71.17, 72.35M)  WoT
    //   [72.35, 77.07M)  WfcT
    float* x2     = (float*)(ws);
    bf16*  vtbuf  = (bf16*)(ws);                      // aliases x2 (live: vtrans..attn)
    bf16*  fcbuf  = (bf16*)(ws + 12582912);
    bf16*  WprojT = (bf16*)(ws + 37748736);
    bf16*  lnbuf  = (bf16*)(ws + 42467328);
    float* parts  = (float*)(ws + 42467328);          // aliases lnbuf+qkv (live: proj..reduce)
    bf16*  qkv    = (bf16*)(ws + 48758784);
    bf16*  WqkvT  = (bf16*)(ws + 67633152);
    bf16*  WoT    = (bf16*)(ws + 71172096);
    bf16*  WfcT   = (bf16*)(ws + 72351744);

    dim3 tb(32, 8);
    transpose_cast_kernel<<<dim3(C3_ / 32, C_ / 32), tb, 0, stream>>>(Wqkv, WqkvT, C_, C3_);
    transpose_cast_kernel<<<dim3(C_ / 32, C_ / 32), tb, 0, stream>>>(Wo, WoT, C_, C_);
    transpose_cast_kernel<<<dim3(C4_ / 32, C_ / 32), tb, 0, stream>>>(Wfc, WfcT, C_, C4_);
    transpose_cast_kernel<<<dim3(C_ / 32, C4_ / 32), tb, 0, stream>>>(Wproj, WprojT, C4_, C_);

    ln_kernel<<<M_, 256, 0, stream>>>(x, ln1_s, ln1_b, lnbuf);

    gemm_kernel<EPI_BF16><<<dim3(576, 1), 256, 0, stream>>>(
        lnbuf, WqkvT, bqkv, nullptr, qkv, C3_, C_, 18);

    vtrans_kernel<<<dim3(T_ / 64, B_ * H_), 256, 0, stream>>>(qkv, vtbuf);

    attn_kernel<<<dim3(768), 256, 0, stream>>>(qkv, vtbuf, lnbuf);

    gemm_kernel<EPI_RES_F32><<<dim3(192, 1), 256, 0, stream>>>(
        lnbuf, WoT, bo, x, x2, C_, C_, 6);

    ln_kernel<<<M_, 256, 0, stream>>>(x2, ln2_s, ln2_b, lnbuf);

    gemm_kernel<EPI_GELU_BF16><<<dim3(768, 1), 256, 0, stream>>>(
        lnbuf, WfcT, bfc, nullptr, fcbuf, C4_, C_, 24);

    gemm_kernel<EPI_PARTIAL><<<dim3(192, 2), 256, 0, stream>>>(
        fcbuf, WprojT, nullptr, nullptr, parts, C_, C4_, 6);

    reduce2_kernel<<<dim3((M_ * C_) / 1024), 256, 0, stream>>>(parts, bproj, x2,
                                                               (float*)d_out);
}